// Round 9
// baseline (425.746 us; speedup 1.0000x reference)
//
#include <hip/hip_runtime.h>
#include <math.h>

#define N_NODES 50000
#define N_EDGES 800000
#define SCAN_NB ((N_NODES + 255) / 256)   // 196
#define VOCAB   30000
#define NT32    ((N_NODES + 31) / 32)     // 1563

typedef __attribute__((ext_vector_type(8)))  short bf16x8;
typedef __attribute__((ext_vector_type(4)))  float f32x4;
typedef __attribute__((ext_vector_type(16))) float f32x16;
typedef __attribute__((ext_vector_type(4)))  int   i32x4;

__device__ inline short f2bf(float f) {
    union { float f; unsigned u; } v; v.f = f;
    unsigned r = v.u + 0x7FFFu + ((v.u >> 16) & 1u);   // RNE
    return (short)(r >> 16);
}
__device__ inline float bflo(unsigned u) { union { unsigned u; float f; } v; v.u = u << 16; return v.f; }
__device__ inline float bfhi(unsigned u) { union { unsigned u; float f; } v; v.u = u & 0xffff0000u; return v.f; }
__device__ inline unsigned cvtpk(float a, float b) {   // lo=bf16(a), hi=bf16(b), RNE
    unsigned r; asm("v_cvt_pk_bf16_f32 %0, %1, %2" : "=v"(r) : "v"(a), "v"(b)); return r;
}
__device__ inline float exp2neg(float x) { float r; asm("v_exp_f32 %0, -%1" : "=v"(r) : "v"(x)); return r; }
__device__ inline float exp2p(float x)   { float r; asm("v_exp_f32 %0, %1"  : "=v"(r) : "v"(x)); return r; }

__device__ inline f32x4 mfma16(bf16x8 a, bf16x8 b, f32x4 c) {
    return __builtin_amdgcn_mfma_f32_16x16x32_bf16(a, b, c, 0, 0, 0);
}
__device__ inline f32x16 mfma32(bf16x8 a, bf16x8 b, f32x16 c) {
    return __builtin_amdgcn_mfma_f32_32x32x16_bf16(a, b, c, 0, 0, 0);
}
__device__ inline bf16x8 asbf(i32x4 v) { union { i32x4 i; bf16x8 b; } u; u.i = v; return u.b; }

// ================================================================ embed -> bf16 table
__global__ void k_embcvt(const float* __restrict__ e, short* __restrict__ o) {
    int i = blockIdx.x * 256 + threadIdx.x;
    if (i >= VOCAB * 64 / 8) return;
    const float4* p = (const float4*)(e + i * 8);
    float4 a = p[0], b = p[1];
    bf16x8 v;
    v[0]=f2bf(a.x); v[1]=f2bf(a.y); v[2]=f2bf(a.z); v[3]=f2bf(a.w);
    v[4]=f2bf(b.x); v[5]=f2bf(b.y); v[6]=f2bf(b.z); v[7]=f2bf(b.w);
    *(bf16x8*)(o + i * 8) = v;
}

// ================================================================ CSR build
__global__ void k_count(const int* __restrict__ ei, int* __restrict__ cnt) {
    int e = blockIdx.x * 256 + threadIdx.x;
    if (e < N_EDGES) atomicAdd(&cnt[ei[N_EDGES + e]], 1);
}
__global__ void k_scan_local(const int* __restrict__ cnt, int* __restrict__ excl,
                             int* __restrict__ bsum) {
    __shared__ int s[256];
    int tid = threadIdx.x;
    int i = blockIdx.x * 256 + tid;
    int v = (i < N_NODES) ? cnt[i] : 0;
    s[tid] = v;
    __syncthreads();
    #pragma unroll
    for (int off = 1; off < 256; off <<= 1) {
        int t = (tid >= off) ? s[tid - off] : 0;
        __syncthreads();
        s[tid] += t;
        __syncthreads();
    }
    if (i < N_NODES) excl[i] = s[tid] - v;
    if (tid == 255) bsum[blockIdx.x] = s[255];
}
__global__ void k_scan_bsum(int* __restrict__ bsum) {
    __shared__ int s[256];
    int tid = threadIdx.x;
    int v = (tid < SCAN_NB) ? bsum[tid] : 0;
    s[tid] = v;
    __syncthreads();
    #pragma unroll
    for (int off = 1; off < 256; off <<= 1) {
        int t = (tid >= off) ? s[tid - off] : 0;
        __syncthreads();
        s[tid] += t;
        __syncthreads();
    }
    if (tid < SCAN_NB) bsum[tid] = s[tid] - v;
}
__global__ void k_make_starts(const int* __restrict__ excl, const int* __restrict__ bsum,
                              const int* __restrict__ cnt,
                              int* __restrict__ starts, int* __restrict__ cursor,
                              float* __restrict__ dinv) {
    int i = blockIdx.x * 256 + threadIdx.x;
    if (i >= N_NODES) return;
    int st = excl[i] + bsum[blockIdx.x];
    starts[i] = st;
    cursor[i] = st;
    dinv[i] = rsqrtf((float)cnt[i] + 1.0f);
}
__global__ void k_fill(const int* __restrict__ ei, int* __restrict__ cursor,
                       int* __restrict__ csr_src) {
    int e = blockIdx.x * 256 + threadIdx.x;
    if (e >= N_EDGES) return;
    int c = ei[N_EDGES + e];
    int p = atomicAdd(&cursor[c], 1);
    csr_src[p] = ei[e];
}

// ================================================================ GRU, transposed orientation (round-7 dataflow, spill-free)
// D = W * x^T / W * h^T : col(lane&31)=node, rows(regs)=output dims.
// pi-permutation of 64 hidden dims: position (p,s,lam,q) <-> dim
//   d = 16*(2p+(s&1)) + 8*lam + 4*(s>>1) + q
// so C/D regs map IN-LANE onto next step's B-fragment slots
// (B k-map: k = 16*ks + 8*l5 + i). h never leaves registers.
// Biases folded via MFMA: acc = biasA-frag (nonzero at k=0) x ones-B-frag.
// W/b pre-scaled by log2e (r,z) / 2*log2e (n) -> raw v_exp_f32 gates.
__global__ __launch_bounds__(256) void k_gru9(
    const int*   __restrict__ xtext,
    const short* __restrict__ embbf,
    const float* __restrict__ w_ih, const float* __restrict__ w_hh,
    const float* __restrict__ b_ih, const float* __restrict__ b_hh,
    unsigned* __restrict__ ht32)    // [N][32] u32: word w = dims (2w, 2w+1)
{
    __shared__ short wfrag[48 * 512];   // 48 frags x 64 lanes x 8 bf16 = 48KB

    const int tid = threadIdx.x;
    // pack A-frags: f = ((side*3+gate)*2+p)*4+ks ; elem i = W'[gate*64+d][16ks+8l5+i]
    for (int u = tid; u < 3072; u += 256) {
        int l = u & 63, f = u >> 6;
        int ks = f & 3, p = (f >> 2) & 1, gate = (f >> 3) % 3, side = f / 24;
        int row = l & 31, wl5 = l >> 5;
        int q = row & 3, s = row >> 3, lam = (row >> 2) & 1;
        int d = 16 * (2 * p + (s & 1)) + 8 * lam + 4 * (s >> 1) + q;
        const float* W = side ? w_hh : w_ih;
        float sc = (gate == 2) ? 2.8853900817779268f : 1.4426950408889634f;
        const float* src = &W[(gate * 64 + d) * 64 + 16 * ks + 8 * wl5];
        short* dst = &wfrag[u * 8];
        #pragma unroll
        for (int i = 0; i < 8; ++i) dst[i] = f2bf(src[i] * sc);
    }
    __syncthreads();

    const int lane = tid & 63;
    const int wave = tid >> 6;
    const int l5 = lane >> 5;
    const int cl = lane & 31;

    const int tile = blockIdx.x * 4 + wave;
    if (tile >= NT32) return;
    const int nbase = tile * 32;
    const int node = min(nbase + cl, N_NODES - 1);
    const int* toks = &xtext[node * 16];

    // bias A-frags in registers: A[row=cl][k] = bias'(d(row,p)) iff k==0
    bf16x8 bfr[2], bfz[2], bfi[2], bfh[2], onesB;
    {
        const float L2E = 1.4426950408889634f;
        int q = cl & 3, s = cl >> 3, lam = (cl >> 2) & 1;
        #pragma unroll
        for (int p = 0; p < 2; ++p) {
            int d = 16 * (2 * p + (s & 1)) + 8 * lam + 4 * (s >> 1) + q;
            i32x4 tr = {0,0,0,0}, tz = {0,0,0,0}, ti = {0,0,0,0}, th = {0,0,0,0};
            if (l5 == 0) {
                tr[0] = (int)cvtpk((b_ih[d] + b_hh[d]) * L2E, 0.0f);
                tz[0] = (int)cvtpk((b_ih[64 + d] + b_hh[64 + d]) * L2E, 0.0f);
                ti[0] = (int)cvtpk(b_ih[128 + d] * (2.0f * L2E), 0.0f);
                th[0] = (int)cvtpk(b_hh[128 + d] * (2.0f * L2E), 0.0f);
            }
            bfr[p] = asbf(tr); bfz[p] = asbf(tz); bfi[p] = asbf(ti); bfh[p] = asbf(th);
        }
        i32x4 to = {0,0,0,0};
        if (l5 == 0) to[0] = 0x3F80;    // bf16 1.0 at k=0
        onesB = asbf(to);
    }

    const bf16x8* WF = (const bf16x8*)wfrag;
#define WIDX(side, gate, p, ks) (((((side)*3+(gate))*2+(p))*4+(ks))*64 + lane)

    const f32x16 z16 = (f32x16)(0.0f);

    bf16x8 eA[4], eN[4];
    i32x4 hU[4], hV[4];

#define LOADE(DST, T) { int tok_ = toks[T]; const short* er_ = &embbf[tok_ * 64 + 8 * l5]; \
    DST[0] = *(const bf16x8*)(er_);      DST[1] = *(const bf16x8*)(er_ + 16); \
    DST[2] = *(const bf16x8*)(er_ + 32); DST[3] = *(const bf16x8*)(er_ + 48); }

#define STEP(T, EC, EP, HO, HN, FIRST, LAST) { \
    if (!(LAST)) LOADE(EP, (T) + 1); \
    _Pragma("unroll") \
    for (int p = 0; p < 2; ++p) { \
        f32x16 ar = mfma32(bfr[p], onesB, z16); \
        f32x16 az = mfma32(bfz[p], onesB, z16); \
        f32x16 ai = mfma32(bfi[p], onesB, z16); \
        f32x16 ah = mfma32(bfh[p], onesB, z16); \
        _Pragma("unroll") \
        for (int ks = 0; ks < 4; ++ks) { \
            ar = mfma32(WF[WIDX(0,0,p,ks)], EC[ks], ar); \
            az = mfma32(WF[WIDX(0,1,p,ks)], EC[ks], az); \
            ai = mfma32(WF[WIDX(0,2,p,ks)], EC[ks], ai); \
        } \
        if (!(FIRST)) { \
            _Pragma("unroll") \
            for (int ks = 0; ks < 4; ++ks) { \
                bf16x8 hf_ = asbf(HO[ks]); \
                ar = mfma32(WF[WIDX(1,0,p,ks)], hf_, ar); \
                az = mfma32(WF[WIDX(1,1,p,ks)], hf_, az); \
                ah = mfma32(WF[WIDX(1,2,p,ks)], hf_, ah); \
            } \
        } \
        _Pragma("unroll") \
        for (int s = 0; s < 4; ++s) { \
            _Pragma("unroll") \
            for (int qq = 0; qq < 2; ++qq) { \
                const int ks2 = 2*p + (s&1); \
                const int jj  = 2*(s>>1) + qq; \
                const int g0  = 4*s + 2*qq; \
                float r0 = __builtin_amdgcn_rcpf(1.0f + exp2neg(ar[g0])); \
                float r1 = __builtin_amdgcn_rcpf(1.0f + exp2neg(ar[g0+1])); \
                float z0 = __builtin_amdgcn_rcpf(1.0f + exp2neg(az[g0])); \
                float z1 = __builtin_amdgcn_rcpf(1.0f + exp2neg(az[g0+1])); \
                float v0 = ai[g0]   + r0 * ah[g0]; \
                float v1 = ai[g0+1] + r1 * ah[g0+1]; \
                float n0 = 1.0f - 2.0f * __builtin_amdgcn_rcpf(exp2p(v0) + 1.0f); \
                float n1 = 1.0f - 2.0f * __builtin_amdgcn_rcpf(exp2p(v1) + 1.0f); \
                float ho0 = (FIRST) ? 0.0f : bflo((unsigned)HO[ks2][jj]); \
                float ho1 = (FIRST) ? 0.0f : bfhi((unsigned)HO[ks2][jj]); \
                float h0 = n0 + z0 * (ho0 - n0); \
                float h1 = n1 + z1 * (ho1 - n1); \
                HN[ks2][jj] = (int)cvtpk(h0, h1); \
            } \
        } \
    } \
}

    LOADE(eA, 0);
    STEP(0, eA, eN, hU, hU, true, false)          // t=0 (no Gh), prefetch t=1 -> eN

    #pragma unroll 1
    for (int tt = 0; tt < 7; ++tt) {              // rolled: 2 steps/body
        int t1 = 1 + 2 * tt;
        STEP(t1,     eN, eA, hU, hV, false, false)
        STEP(t1 + 1, eA, eN, hV, hU, false, false)
    }
    STEP(15, eN, eA, hU, hV, false, true)         // hV = h16

    if (nbase + cl < N_NODES) {
        unsigned* orow = &ht32[(unsigned)(nbase + cl) * 32];
        #pragma unroll
        for (int ks = 0; ks < 4; ++ks)
            #pragma unroll
            for (int j = 0; j < 4; ++j)
                orow[ks * 8 + l5 * 4 + j] = (unsigned)hV[ks][j];
    }
#undef STEP
#undef LOADE
#undef WIDX
}

// ================================================================ dense ms = dinv*( [x|ht] @ W1 ), ht packed: word w = dims (2w, 2w+1)
__global__ void k_mm1(const float* __restrict__ x, const unsigned* __restrict__ ht32,
                      const float* __restrict__ W, const float* __restrict__ dinv,
                      float* __restrict__ M) {
    __shared__ float Wl[72 * 64];
    int tid = threadIdx.x;
    for (int i = tid; i < 72 * 64; i += 256) Wl[i] = W[i];
    __syncthreads();
    int j = tid & 63;
    int n = blockIdx.x * 4 + (tid >> 6);
    if (n >= N_NODES) return;
    float acc = 0.0f;
    const float* xr = x + n * 8;
    #pragma unroll
    for (int k = 0; k < 8; ++k) acc += xr[k] * Wl[k * 64 + j];
    const unsigned* hr = ht32 + (unsigned)n * 32;
    #pragma unroll
    for (int w = 0; w < 32; ++w) {
        unsigned u = hr[w];
        acc += bflo(u) * Wl[(8 + 2 * w) * 64 + j];
        acc += bfhi(u) * Wl[(9 + 2 * w) * 64 + j];
    }
    M[n * 64 + j] = dinv[n] * acc;
}

// ================================================================ dense ms = dinv*(X @ W)  (K=64)
__global__ void k_mm64(const float* __restrict__ X, const float* __restrict__ W,
                       const float* __restrict__ dinv, float* __restrict__ M) {
    __shared__ float Wl[64 * 64];
    int tid = threadIdx.x;
    for (int i = tid; i < 64 * 64; i += 256) Wl[i] = W[i];
    __syncthreads();
    int j = tid & 63;
    int n = blockIdx.x * 4 + (tid >> 6);
    if (n >= N_NODES) return;
    const float* xr = X + n * 64;
    float acc = 0.0f;
    #pragma unroll
    for (int k = 0; k < 64; ++k) acc += xr[k] * Wl[k * 64 + j];
    M[n * 64 + j] = dinv[n] * acc;
}

// ================================================================ gather + self + bias + relu (f32 out)
__global__ __launch_bounds__(256) void k_gather(
    const float* __restrict__ ms, const int* __restrict__ csr_src,
    const int* __restrict__ starts, const int* __restrict__ cnt,
    const float* __restrict__ dinv, const float* __restrict__ b,
    float* __restrict__ out)
{
    int n = blockIdx.x * 4 + (threadIdx.x >> 6);
    if (n >= N_NODES) return;
    int j = threadIdx.x & 63;
    int c = cnt[n];
    const int* lst = csr_src + starts[n];
    float acc = ms[n * 64 + j];
    int k = 0;
    for (; k + 8 <= c; k += 8) {
        int r[8];
        #pragma unroll
        for (int u = 0; u < 8; ++u) r[u] = lst[k + u];
        #pragma unroll
        for (int u = 0; u < 8; ++u) acc += ms[r[u] * 64 + j];
    }
    for (; k < c; ++k) acc += ms[lst[k] * 64 + j];
    float v = dinv[n] * acc + b[j];
    out[n * 64 + j] = fmaxf(v, 0.0f);
}

// ================================================================ gather variant writing bf16 (feeds edge classifier)
__global__ __launch_bounds__(256) void k_gather_bf(
    const float* __restrict__ ms, const int* __restrict__ csr_src,
    const int* __restrict__ starts, const int* __restrict__ cnt,
    const float* __restrict__ dinv, const float* __restrict__ b,
    short* __restrict__ out)
{
    int n = blockIdx.x * 4 + (threadIdx.x >> 6);
    if (n >= N_NODES) return;
    int j = threadIdx.x & 63;
    int c = cnt[n];
    const int* lst = csr_src + starts[n];
    float acc = ms[n * 64 + j];
    int k = 0;
    for (; k + 8 <= c; k += 8) {
        int r[8];
        #pragma unroll
        for (int u = 0; u < 8; ++u) r[u] = lst[k + u];
        #pragma unroll
        for (int u = 0; u < 8; ++u) acc += ms[r[u] * 64 + j];
    }
    for (; k < c; ++k) acc += ms[lst[k] * 64 + j];
    float v = dinv[n] * acc + b[j];
    out[n * 64 + j] = f2bf(fmaxf(v, 0.0f));
}

// ================================================================ edge classifier via MFMA (bf16 h2)
__global__ __launch_bounds__(256) void k_edge_mfma(
    const int* __restrict__ ei, const short* __restrict__ h2b,
    const float* __restrict__ Wl1, const float* __restrict__ bl1,
    const float* __restrict__ Wf,  const float* __restrict__ bf,
    float* __restrict__ out)
{
    __shared__ float wl_s[128 * 64];
    const int tid = threadIdx.x;
    for (int i = tid; i < 128 * 64; i += 256) wl_s[i] = Wl1[i];
    __syncthreads();

    const int lane = tid & 63;
    const int wave = tid >> 6;
    const int lg = lane >> 4;
    const int ll = lane & 15;

    bf16x8 B[16];
    #pragma unroll
    for (int ks = 0; ks < 4; ++ks) {
        #pragma unroll
        for (int ct = 0; ct < 4; ++ct) {
            int c  = ct * 16 + ll;
            int kb = ks * 32 + 8 * lg;
            bf16x8 v;
            #pragma unroll
            for (int i = 0; i < 8; ++i) v[i] = f2bf(wl_s[(kb + i) * 64 + c]);
            B[ks * 4 + ct] = v;
        }
    }
    float wf0[4], wf1[4], bl[4];
    #pragma unroll
    for (int ct = 0; ct < 4; ++ct) {
        int c = ct * 16 + ll;
        wf0[ct] = Wf[c * 2 + 0];
        wf1[ct] = Wf[c * 2 + 1];
        bl[ct]  = bl1[c];
    }
    const float bf0 = bf[0], bf1 = bf[1];

    for (int tile = blockIdx.x * 4 + wave; tile < N_EDGES / 16; tile += gridDim.x * 4) {
        const int ebase = tile * 16;
        const int erow  = ebase + ll;
        const int src = ei[erow];
        const int dst = ei[N_EDGES + erow];

        f32x4 acc[4];
        #pragma unroll
        for (int ct = 0; ct < 4; ++ct) acc[ct] = (f32x4){bl[ct], bl[ct], bl[ct], bl[ct]};

        #pragma unroll
        for (int ks = 0; ks < 4; ++ks) {
            const int nd = (ks < 2) ? src : dst;
            bf16x8 A = *(const bf16x8*)&h2b[nd * 64 + (ks & 1) * 32 + 8 * lg];
            #pragma unroll
            for (int ct = 0; ct < 4; ++ct) acc[ct] = mfma16(A, B[ks * 4 + ct], acc[ct]);
        }

        float p0[4], p1[4];
        #pragma unroll
        for (int q = 0; q < 4; ++q) { p0[q] = 0.0f; p1[q] = 0.0f; }
        #pragma unroll
        for (int ct = 0; ct < 4; ++ct) {
            #pragma unroll
            for (int q = 0; q < 4; ++q) {
                float hd = fmaxf(acc[ct][q], 0.0f);
                p0[q] += hd * wf0[ct];
                p1[q] += hd * wf1[ct];
            }
        }
        #pragma unroll
        for (int m = 1; m <= 8; m <<= 1) {
            #pragma unroll
            for (int q = 0; q < 4; ++q) {
                p0[q] += __shfl_xor(p0[q], m, 64);
                p1[q] += __shfl_xor(p1[q], m, 64);
            }
        }
        if (ll < 8) {
            int q = ll >> 1, cls = ll & 1;
            float l0 = p0[q] + bf0, l1 = p1[q] + bf1;
            float mx  = fmaxf(l0, l1);
            float lse = mx + __logf(__expf(l0 - mx) + __expf(l1 - mx));
            float val = (cls ? l1 : l0) - lse;
            out[(ebase + 4 * lg + q) * 2 + cls] = val;
        }
    }
}

// ================================================================ launch
extern "C" void kernel_launch(void* const* d_in, const int* in_sizes, int n_in,
                              void* d_out, int out_size, void* d_ws, size_t ws_size,
                              hipStream_t stream) {
    const float* x     = (const float*)d_in[0];
    const int*   ei    = (const int*)  d_in[1];
    const int*   xtext = (const int*)  d_in[2];
    const float* embed = (const float*)d_in[3];
    const float* w_ih  = (const float*)d_in[4];
    const float* w_hh  = (const float*)d_in[5];
    const float* b_ih  = (const float*)d_in[6];
    const float* b_hh  = (const float*)d_in[7];
    const float* W1    = (const float*)d_in[8];
    const float* b1    = (const float*)d_in[9];
    const float* W2    = (const float*)d_in[10];
    const float* b2    = (const float*)d_in[11];
    const float* Wl1   = (const float*)d_in[12];
    const float* bl1   = (const float*)d_in[13];
    const float* Wf    = (const float*)d_in[14];
    const float* bf    = (const float*)d_in[15];
    float* out = (float*)d_out;

    char* ws = (char*)d_ws;
    size_t off = 0;
    auto alloc = [&](size_t bytes) { char* p = ws + off; off += (bytes + 255) & ~size_t(255); return p; };
    unsigned* ht32   = (unsigned*)alloc(N_NODES * 32 * 4);
    float*    ms     = (float*)   alloc(N_NODES * 64 * 4);
    float*    h1     = (float*)   alloc(N_NODES * 64 * 4);
    short*    h2b    = (short*)   alloc(N_NODES * 64 * 2);
    float*    dinv   = (float*)   alloc(N_NODES * 4);
    int*      cnt    = (int*)     alloc(N_NODES * 4);
    int*      excl   = (int*)     alloc(N_NODES * 4);
    int*      starts = (int*)     alloc(N_NODES * 4);
    int*      cursor = (int*)     alloc(N_NODES * 4);
    int*      bsum   = (int*)     alloc(SCAN_NB * 4);
    int*      csr_src= (int*)     alloc(N_EDGES * 4);
    short*    embbf  = (short*)   alloc(VOCAB * 64 * 2);

    // ---- bf16 embedding table
    k_embcvt<<<(VOCAB * 64 / 8 + 255) / 256, 256, 0, stream>>>(embed, embbf);

    // ---- CSR build (shared by both GCN layers)
    hipMemsetAsync(cnt, 0, N_NODES * 4, stream);
    k_count<<<(N_EDGES + 255) / 256, 256, 0, stream>>>(ei, cnt);
    k_scan_local<<<SCAN_NB, 256, 0, stream>>>(cnt, excl, bsum);
    k_scan_bsum<<<1, 256, 0, stream>>>(bsum);
    k_make_starts<<<SCAN_NB, 256, 0, stream>>>(excl, bsum, cnt, starts, cursor, dinv);
    k_fill<<<(N_EDGES + 255) / 256, 256, 0, stream>>>(ei, cursor, csr_src);

    // ---- text encoder (transposed, h in registers, bias via MFMA)
    k_gru9<<<(NT32 + 3) / 4, 256, 0, stream>>>(xtext, embbf, w_ih, w_hh, b_ih, b_hh, ht32);

    // ---- GCN layer 1
    k_mm1<<<(N_NODES + 3) / 4, 256, 0, stream>>>(x, ht32, W1, dinv, ms);
    k_gather<<<(N_NODES + 3) / 4, 256, 0, stream>>>(ms, csr_src, starts, cnt, dinv, b1, h1);

    // ---- GCN layer 2
    k_mm64<<<(N_NODES + 3) / 4, 256, 0, stream>>>(h1, W2, dinv, ms);
    k_gather_bf<<<(N_NODES + 3) / 4, 256, 0, stream>>>(ms, csr_src, starts, cnt, dinv, b2, h2b);

    // ---- edge classifier (bf16 h2 fragments)
    k_edge_mfma<<<2048, 256, 0, stream>>>(ei, h2b, Wl1, bl1, Wf, bf, out);
}

// Round 10
// 353.402 us; speedup vs baseline: 1.2047x; 1.2047x over previous
//
#include <hip/hip_runtime.h>
#include <math.h>

#define N_NODES 50000
#define N_EDGES 800000
#define SCAN_NB ((N_NODES + 255) / 256)   // 196
#define VOCAB   30000
#define NT32    ((N_NODES + 31) / 32)     // 1563

typedef __attribute__((ext_vector_type(8)))  short bf16x8;
typedef __attribute__((ext_vector_type(4)))  float f32x4;
typedef __attribute__((ext_vector_type(16))) float f32x16;

__device__ inline short f2bf(float f) {
    union { float f; unsigned u; } v; v.f = f;
    unsigned r = v.u + 0x7FFFu + ((v.u >> 16) & 1u);   // RNE
    return (short)(r >> 16);
}
__device__ inline float bflo(unsigned u) { union { unsigned u; float f; } v; v.u = u << 16; return v.f; }
__device__ inline float bfhi(unsigned u) { union { unsigned u; float f; } v; v.u = u & 0xffff0000u; return v.f; }
__device__ inline unsigned cvtpk(float a, float b) {   // lo=bf16(a), hi=bf16(b), RNE
    unsigned r; asm("v_cvt_pk_bf16_f32 %0, %1, %2" : "=v"(r) : "v"(a), "v"(b)); return r;
}
__device__ inline float exp2neg(float x) { float r; asm("v_exp_f32 %0, -%1" : "=v"(r) : "v"(x)); return r; }
__device__ inline float exp2p(float x)   { float r; asm("v_exp_f32 %0, %1"  : "=v"(r) : "v"(x)); return r; }

__device__ inline f32x4 mfma16(bf16x8 a, bf16x8 b, f32x4 c) {
    return __builtin_amdgcn_mfma_f32_16x16x32_bf16(a, b, c, 0, 0, 0);
}
__device__ inline f32x16 mfma32(bf16x8 a, bf16x8 b, f32x16 c) {
    return __builtin_amdgcn_mfma_f32_32x32x16_bf16(a, b, c, 0, 0, 0);
}
__device__ inline f32x16 splat16(float v) {
    f32x16 r;
    #pragma unroll
    for (int i = 0; i < 16; ++i) r[i] = v;
    return r;
}

// ================================================================ embed -> bf16 table
__global__ void k_embcvt(const float* __restrict__ e, short* __restrict__ o) {
    int i = blockIdx.x * 256 + threadIdx.x;
    if (i >= VOCAB * 64 / 8) return;
    const float4* p = (const float4*)(e + i * 8);
    float4 a = p[0], b = p[1];
    bf16x8 v;
    v[0]=f2bf(a.x); v[1]=f2bf(a.y); v[2]=f2bf(a.z); v[3]=f2bf(a.w);
    v[4]=f2bf(b.x); v[5]=f2bf(b.y); v[6]=f2bf(b.z); v[7]=f2bf(b.w);
    *(bf16x8*)(o + i * 8) = v;
}

// ================================================================ CSR build
__global__ void k_count(const int* __restrict__ ei, int* __restrict__ cnt) {
    int e = blockIdx.x * 256 + threadIdx.x;
    if (e < N_EDGES) atomicAdd(&cnt[ei[N_EDGES + e]], 1);
}
__global__ void k_scan_local(const int* __restrict__ cnt, int* __restrict__ excl,
                             int* __restrict__ bsum) {
    __shared__ int s[256];
    int tid = threadIdx.x;
    int i = blockIdx.x * 256 + tid;
    int v = (i < N_NODES) ? cnt[i] : 0;
    s[tid] = v;
    __syncthreads();
    #pragma unroll
    for (int off = 1; off < 256; off <<= 1) {
        int t = (tid >= off) ? s[tid - off] : 0;
        __syncthreads();
        s[tid] += t;
        __syncthreads();
    }
    if (i < N_NODES) excl[i] = s[tid] - v;
    if (tid == 255) bsum[blockIdx.x] = s[255];
}
__global__ void k_scan_bsum(int* __restrict__ bsum) {
    __shared__ int s[256];
    int tid = threadIdx.x;
    int v = (tid < SCAN_NB) ? bsum[tid] : 0;
    s[tid] = v;
    __syncthreads();
    #pragma unroll
    for (int off = 1; off < 256; off <<= 1) {
        int t = (tid >= off) ? s[tid - off] : 0;
        __syncthreads();
        s[tid] += t;
        __syncthreads();
    }
    if (tid < SCAN_NB) bsum[tid] = s[tid] - v;
}
__global__ void k_make_starts(const int* __restrict__ excl, const int* __restrict__ bsum,
                              const int* __restrict__ cnt,
                              int* __restrict__ starts, int* __restrict__ cursor,
                              float* __restrict__ dinv) {
    int i = blockIdx.x * 256 + threadIdx.x;
    if (i >= N_NODES) return;
    int st = excl[i] + bsum[blockIdx.x];
    starts[i] = st;
    cursor[i] = st;
    dinv[i] = rsqrtf((float)cnt[i] + 1.0f);
}
__global__ void k_fill(const int* __restrict__ ei, int* __restrict__ cursor,
                       int* __restrict__ csr_src) {
    int e = blockIdx.x * 256 + threadIdx.x;
    if (e >= N_EDGES) return;
    int c = ei[N_EDGES + e];
    int p = atomicAdd(&cursor[c], 1);
    csr_src[p] = ei[e];
}

// ================================================================ GRU via 32x32x16 MFMA (round-8 proven version, unchanged)
__global__ __launch_bounds__(256) void k_gru8(
    const int*   __restrict__ xtext,
    const short* __restrict__ embbf,
    const float* __restrict__ w_ih, const float* __restrict__ w_hh,
    const float* __restrict__ b_ih, const float* __restrict__ b_hh,
    unsigned* __restrict__ ht32)    // [N][32] u32: word w = dims (w, 32+w)
{
    __shared__ short bfrag[2 * 4 * 6 * 64 * 8];   // 48KB
    __shared__ short hbuf[4][32 * 64];            // 16KB

    const int tid = threadIdx.x;
    const float L2E = 1.4426950408889634f;
    for (int u = tid; u < 3072; u += 256) {
        int l   = u & 63;
        int ct  = (u >> 6) % 6;
        int ks  = (u / 384) % 4;
        int mat = u / 1536;
        const float* W = mat ? w_hh : w_ih;
        float sc = (ct < 4) ? L2E : 2.0f * L2E;
        const float* src = &W[(ct * 32 + (l & 31)) * 64 + ks * 16 + ((l >> 5) << 3)];
        short* dst = &bfrag[u * 8];
        #pragma unroll
        for (int i = 0; i < 8; ++i) dst[i] = f2bf(src[i] * sc);
    }
    __syncthreads();

    const int lane = tid & 63;
    const int wave = tid >> 6;
    const int l5 = lane >> 5;
    const int cl = lane & 31;

    const int tile  = blockIdx.x * 4 + wave;
    if (tile >= NT32) return;
    const int nbase = tile * 32;

    float b_r[2], b_z[2], b_ni[2], b_nh[2];
    #pragma unroll
    for (int p = 0; p < 2; ++p) {
        int j = p * 32 + cl;
        b_r[p]  = (b_ih[j]        + b_hh[j])        * L2E;
        b_z[p]  = (b_ih[64 + j]   + b_hh[64 + j])   * L2E;
        b_ni[p] = b_ih[128 + j] * (2.0f * L2E);
        b_nh[p] = b_hh[128 + j] * (2.0f * L2E);
    }

    const bf16x8* BF = (const bf16x8*)bfrag;
    short* hl = &hbuf[wave][0];

    float hr0[16], hr1[16];
    #pragma unroll
    for (int g = 0; g < 16; ++g) { hr0[g] = 0.0f; hr1[g] = 0.0f; }

    const int node = min(nbase + cl, N_NODES - 1);
    const int* toks = &xtext[node * 16];

    bf16x8 eA[4], eB[4];

#define LOADE(DST, T) { int tok_ = toks[T]; const short* er_ = &embbf[tok_ * 64 + 8 * l5]; \
    DST[0] = *(const bf16x8*)(er_);      DST[1] = *(const bf16x8*)(er_ + 16); \
    DST[2] = *(const bf16x8*)(er_ + 32); DST[3] = *(const bf16x8*)(er_ + 48); }

#define STEP(T, EC, EP, FIRST, LAST) { \
    bf16x8 hA[4]; \
    if (!(FIRST)) { \
        _Pragma("unroll") \
        for (int ks = 0; ks < 4; ++ks) { \
            int o = (ks * 2 + l5) ^ (cl & 7); \
            hA[ks] = *(const bf16x8*)&hl[cl * 64 + o * 8]; \
        } \
    } \
    if (!(LAST)) LOADE(EP, (T) + 1); \
    _Pragma("unroll") \
    for (int p = 0; p < 2; ++p) { \
        f32x16 ar = splat16(b_r[p]); \
        f32x16 az = splat16(b_z[p]); \
        f32x16 ai = splat16(b_ni[p]); \
        f32x16 ah = splat16(b_nh[p]); \
        _Pragma("unroll") \
        for (int ks = 0; ks < 4; ++ks) { \
            ar = mfma32(EC[ks], BF[(ks * 6 + p) * 64 + lane], ar); \
            az = mfma32(EC[ks], BF[(ks * 6 + 2 + p) * 64 + lane], az); \
            ai = mfma32(EC[ks], BF[(ks * 6 + 4 + p) * 64 + lane], ai); \
        } \
        if (!(FIRST)) { \
            _Pragma("unroll") \
            for (int ks = 0; ks < 4; ++ks) { \
                ar = mfma32(hA[ks], BF[((4 + ks) * 6 + p) * 64 + lane], ar); \
                az = mfma32(hA[ks], BF[((4 + ks) * 6 + 2 + p) * 64 + lane], az); \
                ah = mfma32(hA[ks], BF[((4 + ks) * 6 + 4 + p) * 64 + lane], ah); \
            } \
        } \
        float* hrp = p ? hr1 : hr0; \
        _Pragma("unroll") \
        for (int g = 0; g < 16; ++g) { \
            float r = __builtin_amdgcn_rcpf(1.0f + exp2neg(ar[g])); \
            float z = __builtin_amdgcn_rcpf(1.0f + exp2neg(az[g])); \
            float v = ai[g] + r * ah[g]; \
            float n = 1.0f - 2.0f * __builtin_amdgcn_rcpf(exp2p(v) + 1.0f); \
            hrp[g] = n + z * (hrp[g] - n); \
        } \
    } \
    _Pragma("unroll") \
    for (int g = 0; g < 16; ++g) { \
        unsigned u = cvtpk(hr0[g], hr1[g]); \
        int m = (g & 3) + 8 * (g >> 2) + 4 * l5; \
        if (!(LAST)) { \
            int o0 = (cl >> 3) ^ (m & 7); \
            int o1 = (4 + (cl >> 3)) ^ (m & 7); \
            hl[m * 64 + o0 * 8 + (cl & 7)] = (short)u; \
            hl[m * 64 + o1 * 8 + (cl & 7)] = (short)(u >> 16); \
        } else { \
            int n_ = nbase + m; \
            if (n_ < N_NODES) ht32[(unsigned)n_ * 32 + cl] = u; \
        } \
    } \
}

    LOADE(eA, 0);
    STEP(0, eA, eB, true, false)

    #pragma unroll 1
    for (int tt = 0; tt < 7; ++tt) {
        int t1 = 1 + 2 * tt;
        STEP(t1,     eB, eA, false, false)
        STEP(t1 + 1, eA, eB, false, false)
    }
    STEP(15, eB, eA, false, true)

#undef STEP
#undef LOADE
}

// ================================================================ ms = dinv*( [x|ht] @ W1 ), packed bf16 out (word w = dims (w, w+32))
__global__ void k_mm1(const float* __restrict__ x, const unsigned* __restrict__ ht32,
                      const float* __restrict__ W, const float* __restrict__ dinv,
                      unsigned* __restrict__ msb) {
    __shared__ float Wl[72 * 64];
    int tid = threadIdx.x;
    for (int i = tid; i < 72 * 64; i += 256) Wl[i] = W[i];
    __syncthreads();
    int j = tid & 63;
    int n = blockIdx.x * 4 + (tid >> 6);
    if (n >= N_NODES) return;
    float acc = 0.0f;
    const float* xr = x + n * 8;
    #pragma unroll
    for (int k = 0; k < 8; ++k) acc += xr[k] * Wl[k * 64 + j];
    const unsigned* hr = ht32 + (unsigned)n * 32;
    #pragma unroll
    for (int w = 0; w < 32; ++w) {
        unsigned u = hr[w];
        acc += bflo(u) * Wl[(8 + w) * 64 + j];
        acc += bfhi(u) * Wl[(8 + 32 + w) * 64 + j];
    }
    acc *= dinv[n];
    float part = __shfl_xor(acc, 32, 64);   // lane j <-> j^32
    if (j < 32) msb[(unsigned)n * 32 + j] = cvtpk(acc, part);
}

// ================================================================ ms = dinv*(h1 @ W2), h1 packed in, packed out
__global__ void k_mm64b(const unsigned* __restrict__ Xp, const float* __restrict__ W,
                        const float* __restrict__ dinv, unsigned* __restrict__ msb) {
    __shared__ float Wl[64 * 64];
    int tid = threadIdx.x;
    for (int i = tid; i < 64 * 64; i += 256) Wl[i] = W[i];
    __syncthreads();
    int j = tid & 63;
    int n = blockIdx.x * 4 + (tid >> 6);
    if (n >= N_NODES) return;
    const unsigned* xr = Xp + (unsigned)n * 32;
    float acc = 0.0f;
    #pragma unroll
    for (int w = 0; w < 32; ++w) {
        unsigned u = xr[w];
        acc += bflo(u) * Wl[w * 64 + j];
        acc += bfhi(u) * Wl[(w + 32) * 64 + j];
    }
    acc *= dinv[n];
    float part = __shfl_xor(acc, 32, 64);
    if (j < 32) msb[(unsigned)n * 32 + j] = cvtpk(acc, part);
}

// ================================================================ gather (packed bf16 in/out): 2 nodes/wave, 32 lanes each
__global__ __launch_bounds__(256) void k_gather_p(
    const unsigned* __restrict__ msb, const int* __restrict__ csr_src,
    const int* __restrict__ starts, const int* __restrict__ cnt,
    const float* __restrict__ dinv, const float* __restrict__ b,
    unsigned* __restrict__ outp)    // packed: word w = dims (w, w+32)
{
    int n = blockIdx.x * 8 + (threadIdx.x >> 5);
    if (n >= N_NODES) return;
    int w = threadIdx.x & 31;
    int c = cnt[n];
    const int* lst = csr_src + starts[n];
    unsigned us = msb[(unsigned)n * 32 + w];      // self-loop term
    float a0 = bflo(us), a1 = bfhi(us);
    int k = 0;
    for (; k + 4 <= c; k += 4) {
        int r0 = lst[k], r1 = lst[k+1], r2 = lst[k+2], r3 = lst[k+3];
        unsigned u0 = msb[(unsigned)r0 * 32 + w];
        unsigned u1 = msb[(unsigned)r1 * 32 + w];
        unsigned u2 = msb[(unsigned)r2 * 32 + w];
        unsigned u3 = msb[(unsigned)r3 * 32 + w];
        a0 += bflo(u0) + bflo(u1) + bflo(u2) + bflo(u3);
        a1 += bfhi(u0) + bfhi(u1) + bfhi(u2) + bfhi(u3);
    }
    for (; k < c; ++k) {
        unsigned u = msb[(unsigned)lst[k] * 32 + w];
        a0 += bflo(u); a1 += bfhi(u);
    }
    float d = dinv[n];
    float v0 = fmaxf(d * a0 + b[w], 0.0f);
    float v1 = fmaxf(d * a1 + b[w + 32], 0.0f);
    outp[(unsigned)n * 32 + w] = cvtpk(v0, v1);
}

// ================================================================ gather writing true-order bf16 rows (feeds edge classifier)
__global__ __launch_bounds__(256) void k_gather_h2(
    const unsigned* __restrict__ msb, const int* __restrict__ csr_src,
    const int* __restrict__ starts, const int* __restrict__ cnt,
    const float* __restrict__ dinv, const float* __restrict__ b,
    short* __restrict__ out)        // [N][64] bf16, true dim order
{
    int n = blockIdx.x * 8 + (threadIdx.x >> 5);
    if (n >= N_NODES) return;
    int w = threadIdx.x & 31;
    int c = cnt[n];
    const int* lst = csr_src + starts[n];
    unsigned us = msb[(unsigned)n * 32 + w];
    float a0 = bflo(us), a1 = bfhi(us);
    int k = 0;
    for (; k + 4 <= c; k += 4) {
        int r0 = lst[k], r1 = lst[k+1], r2 = lst[k+2], r3 = lst[k+3];
        unsigned u0 = msb[(unsigned)r0 * 32 + w];
        unsigned u1 = msb[(unsigned)r1 * 32 + w];
        unsigned u2 = msb[(unsigned)r2 * 32 + w];
        unsigned u3 = msb[(unsigned)r3 * 32 + w];
        a0 += bflo(u0) + bflo(u1) + bflo(u2) + bflo(u3);
        a1 += bfhi(u0) + bfhi(u1) + bfhi(u2) + bfhi(u3);
    }
    for (; k < c; ++k) {
        unsigned u = msb[(unsigned)lst[k] * 32 + w];
        a0 += bflo(u); a1 += bfhi(u);
    }
    float d = dinv[n];
    float v0 = fmaxf(d * a0 + b[w], 0.0f);
    float v1 = fmaxf(d * a1 + b[w + 32], 0.0f);
    unsigned u = cvtpk(v0, v1);
    out[(unsigned)n * 64 + w]      = (short)u;
    out[(unsigned)n * 64 + 32 + w] = (short)(u >> 16);
}

// ================================================================ edge classifier via MFMA (bf16 h2) — unchanged
__global__ __launch_bounds__(256) void k_edge_mfma(
    const int* __restrict__ ei, const short* __restrict__ h2b,
    const float* __restrict__ Wl1, const float* __restrict__ bl1,
    const float* __restrict__ Wf,  const float* __restrict__ bf,
    float* __restrict__ out)
{
    __shared__ float wl_s[128 * 64];
    const int tid = threadIdx.x;
    for (int i = tid; i < 128 * 64; i += 256) wl_s[i] = Wl1[i];
    __syncthreads();

    const int lane = tid & 63;
    const int wave = tid >> 6;
    const int lg = lane >> 4;
    const int ll = lane & 15;

    bf16x8 B[16];
    #pragma unroll
    for (int ks = 0; ks < 4; ++ks) {
        #pragma unroll
        for (int ct = 0; ct < 4; ++ct) {
            int c  = ct * 16 + ll;
            int kb = ks * 32 + 8 * lg;
            bf16x8 v;
            #pragma unroll
            for (int i = 0; i < 8; ++i) v[i] = f2bf(wl_s[(kb + i) * 64 + c]);
            B[ks * 4 + ct] = v;
        }
    }
    float wf0[4], wf1[4], bl[4];
    #pragma unroll
    for (int ct = 0; ct < 4; ++ct) {
        int c = ct * 16 + ll;
        wf0[ct] = Wf[c * 2 + 0];
        wf1[ct] = Wf[c * 2 + 1];
        bl[ct]  = bl1[c];
    }
    const float bf0 = bf[0], bf1 = bf[1];

    for (int tile = blockIdx.x * 4 + wave; tile < N_EDGES / 16; tile += gridDim.x * 4) {
        const int ebase = tile * 16;
        const int erow  = ebase + ll;
        const int src = ei[erow];
        const int dst = ei[N_EDGES + erow];

        f32x4 acc[4];
        #pragma unroll
        for (int ct = 0; ct < 4; ++ct) acc[ct] = (f32x4){bl[ct], bl[ct], bl[ct], bl[ct]};

        #pragma unroll
        for (int ks = 0; ks < 4; ++ks) {
            const int nd = (ks < 2) ? src : dst;
            bf16x8 A = *(const bf16x8*)&h2b[nd * 64 + (ks & 1) * 32 + 8 * lg];
            #pragma unroll
            for (int ct = 0; ct < 4; ++ct) acc[ct] = mfma16(A, B[ks * 4 + ct], acc[ct]);
        }

        float p0[4], p1[4];
        #pragma unroll
        for (int q = 0; q < 4; ++q) { p0[q] = 0.0f; p1[q] = 0.0f; }
        #pragma unroll
        for (int ct = 0; ct < 4; ++ct) {
            #pragma unroll
            for (int q = 0; q < 4; ++q) {
                float hd = fmaxf(acc[ct][q], 0.0f);
                p0[q] += hd * wf0[ct];
                p1[q] += hd * wf1[ct];
            }
        }
        #pragma unroll
        for (int m = 1; m <= 8; m <<= 1) {
            #pragma unroll
            for (int q = 0; q < 4; ++q) {
                p0[q] += __shfl_xor(p0[q], m, 64);
                p1[q] += __shfl_xor(p1[q], m, 64);
            }
        }
        if (ll < 8) {
            int q = ll >> 1, cls = ll & 1;
            float l0 = p0[q] + bf0, l1 = p1[q] + bf1;
            float mx  = fmaxf(l0, l1);
            float lse = mx + __logf(__expf(l0 - mx) + __expf(l1 - mx));
            float val = (cls ? l1 : l0) - lse;
            out[(ebase + 4 * lg + q) * 2 + cls] = val;
        }
    }
}

// ================================================================ launch
extern "C" void kernel_launch(void* const* d_in, const int* in_sizes, int n_in,
                              void* d_out, int out_size, void* d_ws, size_t ws_size,
                              hipStream_t stream) {
    const float* x     = (const float*)d_in[0];
    const int*   ei    = (const int*)  d_in[1];
    const int*   xtext = (const int*)  d_in[2];
    const float* embed = (const float*)d_in[3];
    const float* w_ih  = (const float*)d_in[4];
    const float* w_hh  = (const float*)d_in[5];
    const float* b_ih  = (const float*)d_in[6];
    const float* b_hh  = (const float*)d_in[7];
    const float* W1    = (const float*)d_in[8];
    const float* b1    = (const float*)d_in[9];
    const float* W2    = (const float*)d_in[10];
    const float* b2    = (const float*)d_in[11];
    const float* Wl1   = (const float*)d_in[12];
    const float* bl1   = (const float*)d_in[13];
    const float* Wf    = (const float*)d_in[14];
    const float* bf    = (const float*)d_in[15];
    float* out = (float*)d_out;

    char* ws = (char*)d_ws;
    size_t off = 0;
    auto alloc = [&](size_t bytes) { char* p = ws + off; off += (bytes + 255) & ~size_t(255); return p; };
    unsigned* ht32   = (unsigned*)alloc(N_NODES * 32 * 4);
    unsigned* msb    = (unsigned*)alloc(N_NODES * 32 * 4);
    unsigned* h1b    = (unsigned*)alloc(N_NODES * 32 * 4);
    short*    h2b    = (short*)   alloc(N_NODES * 64 * 2);
    float*    dinv   = (float*)   alloc(N_NODES * 4);
    int*      cnt    = (int*)     alloc(N_NODES * 4);
    int*      excl   = (int*)     alloc(N_NODES * 4);
    int*      starts = (int*)     alloc(N_NODES * 4);
    int*      cursor = (int*)     alloc(N_NODES * 4);
    int*      bsum   = (int*)     alloc(SCAN_NB * 4);
    int*      csr_src= (int*)     alloc(N_EDGES * 4);
    short*    embbf  = (short*)   alloc(VOCAB * 64 * 2);

    // ---- bf16 embedding table
    k_embcvt<<<(VOCAB * 64 / 8 + 255) / 256, 256, 0, stream>>>(embed, embbf);

    // ---- CSR build (shared by both GCN layers)
    hipMemsetAsync(cnt, 0, N_NODES * 4, stream);
    k_count<<<(N_EDGES + 255) / 256, 256, 0, stream>>>(ei, cnt);
    k_scan_local<<<SCAN_NB, 256, 0, stream>>>(cnt, excl, bsum);
    k_scan_bsum<<<1, 256, 0, stream>>>(bsum);
    k_make_starts<<<SCAN_NB, 256, 0, stream>>>(excl, bsum, cnt, starts, cursor, dinv);
    k_fill<<<(N_EDGES + 255) / 256, 256, 0, stream>>>(ei, cursor, csr_src);

    // ---- text encoder (round-8 proven kernel)
    k_gru8<<<(NT32 + 3) / 4, 256, 0, stream>>>(xtext, embbf, w_ih, w_hh, b_ih, b_hh, ht32);

    // ---- GCN layer 1 (packed bf16 pipeline)
    k_mm1<<<(N_NODES + 3) / 4, 256, 0, stream>>>(x, ht32, W1, dinv, msb);
    k_gather_p<<<(N_NODES + 7) / 8, 256, 0, stream>>>(msb, csr_src, starts, cnt, dinv, b1, h1b);

    // ---- GCN layer 2
    k_mm64b<<<(N_NODES + 3) / 4, 256, 0, stream>>>(h1b, W2, dinv, msb);
    k_gather_h2<<<(N_NODES + 7) / 8, 256, 0, stream>>>(msb, csr_src, starts, cnt, dinv, b2, h2b);

    // ---- edge classifier (bf16 h2 fragments)
    k_edge_mfma<<<2048, 256, 0, stream>>>(ei, h2b, Wl1, bl1, Wf, bf, out);
}

// Round 11
// 307.239 us; speedup vs baseline: 1.3857x; 1.1502x over previous
//
#include <hip/hip_runtime.h>
#include <math.h>

#define N_NODES 50000
#define N_EDGES 800000
#define SCAN_NB ((N_NODES + 255) / 256)   // 196
#define VOCAB   30000
#define NT32    ((N_NODES + 31) / 32)     // 1563

typedef __attribute__((ext_vector_type(8)))  short bf16x8;
typedef __attribute__((ext_vector_type(4)))  float f32x4;
typedef __attribute__((ext_vector_type(16))) float f32x16;
typedef __attribute__((ext_vector_type(4)))  int   i32x4;

__device__ inline short f2bf(float f) {
    union { float f; unsigned u; } v; v.f = f;
    unsigned r = v.u + 0x7FFFu + ((v.u >> 16) & 1u);   // RNE
    return (short)(r >> 16);
}
__device__ inline float bflo(unsigned u) { union { unsigned u; float f; } v; v.u = u << 16; return v.f; }
__device__ inline float bfhi(unsigned u) { union { unsigned u; float f; } v; v.u = u & 0xffff0000u; return v.f; }
__device__ inline unsigned cvtpk(float a, float b) {   // lo=bf16(a), hi=bf16(b), RNE
    unsigned r; asm("v_cvt_pk_bf16_f32 %0, %1, %2" : "=v"(r) : "v"(a), "v"(b)); return r;
}
__device__ inline float exp2neg(float x) { float r; asm("v_exp_f32 %0, -%1" : "=v"(r) : "v"(x)); return r; }
__device__ inline float exp2p(float x)   { float r; asm("v_exp_f32 %0, %1"  : "=v"(r) : "v"(x)); return r; }

__device__ inline f32x4 mfma16(bf16x8 a, bf16x8 b, f32x4 c) {
    return __builtin_amdgcn_mfma_f32_16x16x32_bf16(a, b, c, 0, 0, 0);
}
__device__ inline f32x16 mfma32(bf16x8 a, bf16x8 b, f32x16 c) {
    return __builtin_amdgcn_mfma_f32_32x32x16_bf16(a, b, c, 0, 0, 0);
}
__device__ inline f32x16 splat16(float v) {
    f32x16 r;
    #pragma unroll
    for (int i = 0; i < 16; ++i) r[i] = v;
    return r;
}
__device__ inline bf16x8 asbf(i32x4 v) { union { i32x4 i; bf16x8 b; } u; u.i = v; return u.b; }

// ================================================================ embed -> bf16 table
__global__ void k_embcvt(const float* __restrict__ e, short* __restrict__ o) {
    int i = blockIdx.x * 256 + threadIdx.x;
    if (i >= VOCAB * 64 / 8) return;
    const float4* p = (const float4*)(e + i * 8);
    float4 a = p[0], b = p[1];
    bf16x8 v;
    v[0]=f2bf(a.x); v[1]=f2bf(a.y); v[2]=f2bf(a.z); v[3]=f2bf(a.w);
    v[4]=f2bf(b.x); v[5]=f2bf(b.y); v[6]=f2bf(b.z); v[7]=f2bf(b.w);
    *(bf16x8*)(o + i * 8) = v;
}

// ================================================================ CSR build
__global__ void k_count(const int* __restrict__ ei, int* __restrict__ cnt) {
    int e = blockIdx.x * 256 + threadIdx.x;
    if (e < N_EDGES) atomicAdd(&cnt[ei[N_EDGES + e]], 1);
}
__global__ void k_scan_local(const int* __restrict__ cnt, int* __restrict__ excl,
                             int* __restrict__ bsum) {
    __shared__ int s[256];
    int tid = threadIdx.x;
    int i = blockIdx.x * 256 + tid;
    int v = (i < N_NODES) ? cnt[i] : 0;
    s[tid] = v;
    __syncthreads();
    #pragma unroll
    for (int off = 1; off < 256; off <<= 1) {
        int t = (tid >= off) ? s[tid - off] : 0;
        __syncthreads();
        s[tid] += t;
        __syncthreads();
    }
    if (i < N_NODES) excl[i] = s[tid] - v;
    if (tid == 255) bsum[blockIdx.x] = s[255];
}
__global__ void k_scan_bsum(int* __restrict__ bsum) {
    __shared__ int s[256];
    int tid = threadIdx.x;
    int v = (tid < SCAN_NB) ? bsum[tid] : 0;
    s[tid] = v;
    __syncthreads();
    #pragma unroll
    for (int off = 1; off < 256; off <<= 1) {
        int t = (tid >= off) ? s[tid - off] : 0;
        __syncthreads();
        s[tid] += t;
        __syncthreads();
    }
    if (tid < SCAN_NB) bsum[tid] = s[tid] - v;
}
__global__ void k_make_starts(const int* __restrict__ excl, const int* __restrict__ bsum,
                              const int* __restrict__ cnt,
                              int* __restrict__ starts, int* __restrict__ cursor,
                              float* __restrict__ dinv) {
    int i = blockIdx.x * 256 + threadIdx.x;
    if (i >= N_NODES) return;
    int st = excl[i] + bsum[blockIdx.x];
    starts[i] = st;
    cursor[i] = st;
    dinv[i] = rsqrtf((float)cnt[i] + 1.0f);
}
__global__ void k_fill(const int* __restrict__ ei, int* __restrict__ cursor,
                       int* __restrict__ csr_src) {
    int e = blockIdx.x * 256 + threadIdx.x;
    if (e >= N_EDGES) return;
    int c = ei[N_EDGES + e];
    int p = atomicAdd(&cursor[c], 1);
    csr_src[p] = ei[e];
}

// ================================================================ GRU via 32x32x16 MFMA (round-8 proven version, unchanged)
__global__ __launch_bounds__(256) void k_gru8(
    const int*   __restrict__ xtext,
    const short* __restrict__ embbf,
    const float* __restrict__ w_ih, const float* __restrict__ w_hh,
    const float* __restrict__ b_ih, const float* __restrict__ b_hh,
    unsigned* __restrict__ ht32)    // [N][32] u32: word w = dims (w, 32+w)
{
    __shared__ short bfrag[2 * 4 * 6 * 64 * 8];   // 48KB
    __shared__ short hbuf[4][32 * 64];            // 16KB

    const int tid = threadIdx.x;
    const float L2E = 1.4426950408889634f;
    for (int u = tid; u < 3072; u += 256) {
        int l   = u & 63;
        int ct  = (u >> 6) % 6;
        int ks  = (u / 384) % 4;
        int mat = u / 1536;
        const float* W = mat ? w_hh : w_ih;
        float sc = (ct < 4) ? L2E : 2.0f * L2E;
        const float* src = &W[(ct * 32 + (l & 31)) * 64 + ks * 16 + ((l >> 5) << 3)];
        short* dst = &bfrag[u * 8];
        #pragma unroll
        for (int i = 0; i < 8; ++i) dst[i] = f2bf(src[i] * sc);
    }
    __syncthreads();

    const int lane = tid & 63;
    const int wave = tid >> 6;
    const int l5 = lane >> 5;
    const int cl = lane & 31;

    const int tile  = blockIdx.x * 4 + wave;
    if (tile >= NT32) return;
    const int nbase = tile * 32;

    float b_r[2], b_z[2], b_ni[2], b_nh[2];
    #pragma unroll
    for (int p = 0; p < 2; ++p) {
        int j = p * 32 + cl;
        b_r[p]  = (b_ih[j]        + b_hh[j])        * L2E;
        b_z[p]  = (b_ih[64 + j]   + b_hh[64 + j])   * L2E;
        b_ni[p] = b_ih[128 + j] * (2.0f * L2E);
        b_nh[p] = b_hh[128 + j] * (2.0f * L2E);
    }

    const bf16x8* BF = (const bf16x8*)bfrag;
    short* hl = &hbuf[wave][0];

    float hr0[16], hr1[16];
    #pragma unroll
    for (int g = 0; g < 16; ++g) { hr0[g] = 0.0f; hr1[g] = 0.0f; }

    const int node = min(nbase + cl, N_NODES - 1);
    const int* toks = &xtext[node * 16];

    bf16x8 eA[4], eB[4];

#define LOADE(DST, T) { int tok_ = toks[T]; const short* er_ = &embbf[tok_ * 64 + 8 * l5]; \
    DST[0] = *(const bf16x8*)(er_);      DST[1] = *(const bf16x8*)(er_ + 16); \
    DST[2] = *(const bf16x8*)(er_ + 32); DST[3] = *(const bf16x8*)(er_ + 48); }

#define STEP(T, EC, EP, FIRST, LAST) { \
    bf16x8 hA[4]; \
    if (!(FIRST)) { \
        _Pragma("unroll") \
        for (int ks = 0; ks < 4; ++ks) { \
            int o = (ks * 2 + l5) ^ (cl & 7); \
            hA[ks] = *(const bf16x8*)&hl[cl * 64 + o * 8]; \
        } \
    } \
    if (!(LAST)) LOADE(EP, (T) + 1); \
    _Pragma("unroll") \
    for (int p = 0; p < 2; ++p) { \
        f32x16 ar = splat16(b_r[p]); \
        f32x16 az = splat16(b_z[p]); \
        f32x16 ai = splat16(b_ni[p]); \
        f32x16 ah = splat16(b_nh[p]); \
        _Pragma("unroll") \
        for (int ks = 0; ks < 4; ++ks) { \
            ar = mfma32(EC[ks], BF[(ks * 6 + p) * 64 + lane], ar); \
            az = mfma32(EC[ks], BF[(ks * 6 + 2 + p) * 64 + lane], az); \
            ai = mfma32(EC[ks], BF[(ks * 6 + 4 + p) * 64 + lane], ai); \
        } \
        if (!(FIRST)) { \
            _Pragma("unroll") \
            for (int ks = 0; ks < 4; ++ks) { \
                ar = mfma32(hA[ks], BF[((4 + ks) * 6 + p) * 64 + lane], ar); \
                az = mfma32(hA[ks], BF[((4 + ks) * 6 + 2 + p) * 64 + lane], az); \
                ah = mfma32(hA[ks], BF[((4 + ks) * 6 + 4 + p) * 64 + lane], ah); \
            } \
        } \
        float* hrp = p ? hr1 : hr0; \
        _Pragma("unroll") \
        for (int g = 0; g < 16; ++g) { \
            float r = __builtin_amdgcn_rcpf(1.0f + exp2neg(ar[g])); \
            float z = __builtin_amdgcn_rcpf(1.0f + exp2neg(az[g])); \
            float v = ai[g] + r * ah[g]; \
            float n = 1.0f - 2.0f * __builtin_amdgcn_rcpf(exp2p(v) + 1.0f); \
            hrp[g] = n + z * (hrp[g] - n); \
        } \
    } \
    _Pragma("unroll") \
    for (int g = 0; g < 16; ++g) { \
        unsigned u = cvtpk(hr0[g], hr1[g]); \
        int m = (g & 3) + 8 * (g >> 2) + 4 * l5; \
        if (!(LAST)) { \
            int o0 = (cl >> 3) ^ (m & 7); \
            int o1 = (4 + (cl >> 3)) ^ (m & 7); \
            hl[m * 64 + o0 * 8 + (cl & 7)] = (short)u; \
            hl[m * 64 + o1 * 8 + (cl & 7)] = (short)(u >> 16); \
        } else { \
            int n_ = nbase + m; \
            if (n_ < N_NODES) ht32[(unsigned)n_ * 32 + cl] = u; \
        } \
    } \
}

    LOADE(eA, 0);
    STEP(0, eA, eB, true, false)

    #pragma unroll 1
    for (int tt = 0; tt < 7; ++tt) {
        int t1 = 1 + 2 * tt;
        STEP(t1,     eB, eA, false, false)
        STEP(t1 + 1, eA, eB, false, false)
    }
    STEP(15, eB, eA, false, true)

#undef STEP
#undef LOADE
}

// ================================================================ MFMA mm1: msb = dinv*( [x|ht] @ W1 ), K padded 72->80
// A: row=lane&31=node, k=16ks+8*l5+i (ks<4: ht dims from packed words;
// ks=4: l5==0 -> x dims 0-7, l5==1 -> zeros). B: W1 frags, same k-map.
// C/D: col=lane&31 = out-dim (pass p -> dim 32p+cl), row g -> node.
__global__ __launch_bounds__(256) void k_mm1_mf(
    const float* __restrict__ x, const unsigned* __restrict__ ht32,
    const float* __restrict__ W1, const float* __restrict__ dinv,
    unsigned* __restrict__ msb)
{
    __shared__ short bfw[2 * 5 * 64 * 8];   // 10KB  frag f=p*5+ks
    const int tid = threadIdx.x;
    for (int u = tid; u < 640; u += 256) {
        int l = u & 63, f = u >> 6;
        int ks = f % 5, p = f / 5;
        int c = p * 32 + (l & 31);
        int wl5 = l >> 5;
        short* dst = &bfw[u * 8];
        if (ks < 4) {
            const float* src = &W1[(8 + ks * 16 + 8 * wl5) * 64 + c];
            #pragma unroll
            for (int i = 0; i < 8; ++i) dst[i] = f2bf(src[i * 64]);
        } else {
            #pragma unroll
            for (int i = 0; i < 8; ++i) dst[i] = (wl5 == 0) ? f2bf(W1[i * 64 + c]) : (short)0;
        }
    }
    __syncthreads();

    const int lane = tid & 63;
    const int wave = tid >> 6;
    const int l5 = lane >> 5;
    const int cl = lane & 31;
    const int tile = blockIdx.x * 4 + wave;
    if (tile >= NT32) return;
    const int nbase = tile * 32;
    const int node = min(nbase + cl, N_NODES - 1);

    const uint4* hp = (const uint4*)(ht32 + (unsigned)node * 32);
    uint4 A0 = hp[2 * l5], A1 = hp[2 * l5 + 1];       // words 8l5..8l5+7
    uint4 A2 = hp[4 + 2 * l5], A3 = hp[5 + 2 * l5];   // words 16+8l5..+7
    const float4* xp = (const float4*)(x + (size_t)node * 8);
    float4 x0 = xp[0], x1 = xp[1];

    unsigned w0[8] = {A0.x, A0.y, A0.z, A0.w, A1.x, A1.y, A1.z, A1.w};
    unsigned w1[8] = {A2.x, A2.y, A2.z, A2.w, A3.x, A3.y, A3.z, A3.w};

    bf16x8 fa[5];
    {
        i32x4 t;
        #pragma unroll
        for (int i = 0; i < 4; ++i) t[i] = (int)((w0[2*i] & 0xffffu) | (w0[2*i+1] << 16));
        fa[0] = asbf(t);
        #pragma unroll
        for (int i = 0; i < 4; ++i) t[i] = (int)((w1[2*i] & 0xffffu) | (w1[2*i+1] << 16));
        fa[1] = asbf(t);
        #pragma unroll
        for (int i = 0; i < 4; ++i) t[i] = (int)((w0[2*i] >> 16) | (w0[2*i+1] & 0xffff0000u));
        fa[2] = asbf(t);
        #pragma unroll
        for (int i = 0; i < 4; ++i) t[i] = (int)((w1[2*i] >> 16) | (w1[2*i+1] & 0xffff0000u));
        fa[3] = asbf(t);
        if (l5 == 0) {
            t[0] = (int)cvtpk(x0.x, x0.y); t[1] = (int)cvtpk(x0.z, x0.w);
            t[2] = (int)cvtpk(x1.x, x1.y); t[3] = (int)cvtpk(x1.z, x1.w);
        } else {
            t[0] = t[1] = t[2] = t[3] = 0;
        }
        fa[4] = asbf(t);
    }

    const bf16x8* BW = (const bf16x8*)bfw;
    f32x16 a0 = (f32x16)(0.0f), a1 = (f32x16)(0.0f);
    #pragma unroll
    for (int ks = 0; ks < 5; ++ks) {
        a0 = mfma32(fa[ks], BW[ks * 64 + lane], a0);
        a1 = mfma32(fa[ks], BW[(5 + ks) * 64 + lane], a1);
    }

    #pragma unroll
    for (int g = 0; g < 16; ++g) {
        int m = (g & 3) + 8 * (g >> 2) + 4 * l5;
        int n = nbase + m;
        if (n < N_NODES) {
            float dv = dinv[n];
            msb[(unsigned)n * 32 + cl] = cvtpk(a0[g] * dv, a1[g] * dv);
        }
    }
}

// ================================================================ MFMA mm2: msb = dinv*(h1 @ W2), h1 packed in
__global__ __launch_bounds__(256) void k_mm2_mf(
    const unsigned* __restrict__ h1b, const float* __restrict__ W2,
    const float* __restrict__ dinv, unsigned* __restrict__ msb)
{
    __shared__ short bfw[2 * 4 * 64 * 8];   // 8KB  frag f=p*4+ks
    const int tid = threadIdx.x;
    for (int u = tid; u < 512; u += 256) {
        int l = u & 63, f = u >> 6;
        int ks = f & 3, p = f >> 2;
        int c = p * 32 + (l & 31);
        int wl5 = l >> 5;
        const float* src = &W2[(ks * 16 + 8 * wl5) * 64 + c];
        short* dst = &bfw[u * 8];
        #pragma unroll
        for (int i = 0; i < 8; ++i) dst[i] = f2bf(src[i * 64]);
    }
    __syncthreads();

    const int lane = tid & 63;
    const int wave = tid >> 6;
    const int l5 = lane >> 5;
    const int cl = lane & 31;
    const int tile = blockIdx.x * 4 + wave;
    if (tile >= NT32) return;
    const int nbase = tile * 32;
    const int node = min(nbase + cl, N_NODES - 1);

    const uint4* hp = (const uint4*)(h1b + (unsigned)node * 32);
    uint4 A0 = hp[2 * l5], A1 = hp[2 * l5 + 1];
    uint4 A2 = hp[4 + 2 * l5], A3 = hp[5 + 2 * l5];

    unsigned w0[8] = {A0.x, A0.y, A0.z, A0.w, A1.x, A1.y, A1.z, A1.w};
    unsigned w1[8] = {A2.x, A2.y, A2.z, A2.w, A3.x, A3.y, A3.z, A3.w};

    bf16x8 fa[4];
    {
        i32x4 t;
        #pragma unroll
        for (int i = 0; i < 4; ++i) t[i] = (int)((w0[2*i] & 0xffffu) | (w0[2*i+1] << 16));
        fa[0] = asbf(t);
        #pragma unroll
        for (int i = 0; i < 4; ++i) t[i] = (int)((w1[2*i] & 0xffffu) | (w1[2*i+1] << 16));
        fa[1] = asbf(t);
        #pragma unroll
        for (int i = 0; i < 4; ++i) t[i] = (int)((w0[2*i] >> 16) | (w0[2*i+1] & 0xffff0000u));
        fa[2] = asbf(t);
        #pragma unroll
        for (int i = 0; i < 4; ++i) t[i] = (int)((w1[2*i] >> 16) | (w1[2*i+1] & 0xffff0000u));
        fa[3] = asbf(t);
    }

    const bf16x8* BW = (const bf16x8*)bfw;
    f32x16 a0 = (f32x16)(0.0f), a1 = (f32x16)(0.0f);
    #pragma unroll
    for (int ks = 0; ks < 4; ++ks) {
        a0 = mfma32(fa[ks], BW[ks * 64 + lane], a0);
        a1 = mfma32(fa[ks], BW[(4 + ks) * 64 + lane], a1);
    }

    #pragma unroll
    for (int g = 0; g < 16; ++g) {
        int m = (g & 3) + 8 * (g >> 2) + 4 * l5;
        int n = nbase + m;
        if (n < N_NODES) {
            float dv = dinv[n];
            msb[(unsigned)n * 32 + cl] = cvtpk(a0[g] * dv, a1[g] * dv);
        }
    }
}

// ================================================================ gather (packed bf16 in/out): 2 nodes/wave, 32 lanes each
__global__ __launch_bounds__(256) void k_gather_p(
    const unsigned* __restrict__ msb, const int* __restrict__ csr_src,
    const int* __restrict__ starts, const int* __restrict__ cnt,
    const float* __restrict__ dinv, const float* __restrict__ b,
    unsigned* __restrict__ outp)    // packed: word w = dims (w, w+32)
{
    int n = blockIdx.x * 8 + (threadIdx.x >> 5);
    if (n >= N_NODES) return;
    int w = threadIdx.x & 31;
    int c = cnt[n];
    const int* lst = csr_src + starts[n];
    unsigned us = msb[(unsigned)n * 32 + w];      // self-loop term
    float a0 = bflo(us), a1 = bfhi(us);
    int k = 0;
    for (; k + 4 <= c; k += 4) {
        int r0 = lst[k], r1 = lst[k+1], r2 = lst[k+2], r3 = lst[k+3];
        unsigned u0 = msb[(unsigned)r0 * 32 + w];
        unsigned u1 = msb[(unsigned)r1 * 32 + w];
        unsigned u2 = msb[(unsigned)r2 * 32 + w];
        unsigned u3 = msb[(unsigned)r3 * 32 + w];
        a0 += bflo(u0) + bflo(u1) + bflo(u2) + bflo(u3);
        a1 += bfhi(u0) + bfhi(u1) + bfhi(u2) + bfhi(u3);
    }
    for (; k < c; ++k) {
        unsigned u = msb[(unsigned)lst[k] * 32 + w];
        a0 += bflo(u); a1 += bfhi(u);
    }
    float d = dinv[n];
    float v0 = fmaxf(d * a0 + b[w], 0.0f);
    float v1 = fmaxf(d * a1 + b[w + 32], 0.0f);
    outp[(unsigned)n * 32 + w] = cvtpk(v0, v1);
}

// ================================================================ gather writing true-order bf16 rows (feeds edge classifier)
__global__ __launch_bounds__(256) void k_gather_h2(
    const unsigned* __restrict__ msb, const int* __restrict__ csr_src,
    const int* __restrict__ starts, const int* __restrict__ cnt,
    const float* __restrict__ dinv, const float* __restrict__ b,
    short* __restrict__ out)        // [N][64] bf16, true dim order
{
    int n = blockIdx.x * 8 + (threadIdx.x >> 5);
    if (n >= N_NODES) return;
    int w = threadIdx.x & 31;
    int c = cnt[n];
    const int* lst = csr_src + starts[n];
    unsigned us = msb[(unsigned)n * 32 + w];
    float a0 = bflo(us), a1 = bfhi(us);
    int k = 0;
    for (; k + 4 <= c; k += 4) {
        int r0 = lst[k], r1 = lst[k+1], r2 = lst[k+2], r3 = lst[k+3];
        unsigned u0 = msb[(unsigned)r0 * 32 + w];
        unsigned u1 = msb[(unsigned)r1 * 32 + w];
        unsigned u2 = msb[(unsigned)r2 * 32 + w];
        unsigned u3 = msb[(unsigned)r3 * 32 + w];
        a0 += bflo(u0) + bflo(u1) + bflo(u2) + bflo(u3);
        a1 += bfhi(u0) + bfhi(u1) + bfhi(u2) + bfhi(u3);
    }
    for (; k < c; ++k) {
        unsigned u = msb[(unsigned)lst[k] * 32 + w];
        a0 += bflo(u); a1 += bfhi(u);
    }
    float d = dinv[n];
    float v0 = fmaxf(d * a0 + b[w], 0.0f);
    float v1 = fmaxf(d * a1 + b[w + 32], 0.0f);
    unsigned u = cvtpk(v0, v1);
    out[(unsigned)n * 64 + w]      = (short)u;
    out[(unsigned)n * 64 + 32 + w] = (short)(u >> 16);
}

// ================================================================ edge classifier via MFMA (bf16 h2) — unchanged
__global__ __launch_bounds__(256) void k_edge_mfma(
    const int* __restrict__ ei, const short* __restrict__ h2b,
    const float* __restrict__ Wl1, const float* __restrict__ bl1,
    const float* __restrict__ Wf,  const float* __restrict__ bf,
    float* __restrict__ out)
{
    __shared__ float wl_s[128 * 64];
    const int tid = threadIdx.x;
    for (int i = tid; i < 128 * 64; i += 256) wl_s[i] = Wl1[i];
    __syncthreads();

    const int lane = tid & 63;
    const int wave = tid >> 6;
    const int lg = lane >> 4;
    const int ll = lane & 15;

    bf16x8 B[16];
    #pragma unroll
    for (int ks = 0; ks < 4; ++ks) {
        #pragma unroll
        for (int ct = 0; ct < 4; ++ct) {
            int c  = ct * 16 + ll;
            int kb = ks * 32 + 8 * lg;
            bf16x8 v;
            #pragma unroll
            for (int i = 0; i < 8; ++i) v[i] = f2bf(wl_s[(kb + i) * 64 + c]);
            B[ks * 4 + ct] = v;
        }
    }
    float wf0[4], wf1[4], bl[4];
    #pragma unroll
    for (int ct = 0; ct < 4; ++ct) {
        int c = ct * 16 + ll;
        wf0[ct] = Wf[c * 2 + 0];
        wf1[ct] = Wf[c * 2 + 1];
        bl[ct]  = bl1[c];
    }
    const float bf0 = bf[0], bf1 = bf[1];

    for (int tile = blockIdx.x * 4 + wave; tile < N_EDGES / 16; tile += gridDim.x * 4) {
        const int ebase = tile * 16;
        const int erow  = ebase + ll;
        const int src = ei[erow];
        const int dst = ei[N_EDGES + erow];

        f32x4 acc[4];
        #pragma unroll
        for (int ct = 0; ct < 4; ++ct) acc[ct] = (f32x4){bl[ct], bl[ct], bl[ct], bl[ct]};

        #pragma unroll
        for (int ks = 0; ks < 4; ++ks) {
            const int nd = (ks < 2) ? src : dst;
            bf16x8 A = *(const bf16x8*)&h2b[nd * 64 + (ks & 1) * 32 + 8 * lg];
            #pragma unroll
            for (int ct = 0; ct < 4; ++ct) acc[ct] = mfma16(A, B[ks * 4 + ct], acc[ct]);
        }

        float p0[4], p1[4];
        #pragma unroll
        for (int q = 0; q < 4; ++q) { p0[q] = 0.0f; p1[q] = 0.0f; }
        #pragma unroll
        for (int ct = 0; ct < 4; ++ct) {
            #pragma unroll
            for (int q = 0; q < 4; ++q) {
                float hd = fmaxf(acc[ct][q], 0.0f);
                p0[q] += hd * wf0[ct];
                p1[q] += hd * wf1[ct];
            }
        }
        #pragma unroll
        for (int m = 1; m <= 8; m <<= 1) {
            #pragma unroll
            for (int q = 0; q < 4; ++q) {
                p0[q] += __shfl_xor(p0[q], m, 64);
                p1[q] += __shfl_xor(p1[q], m, 64);
            }
        }
        if (ll < 8) {
            int q = ll >> 1, cls = ll & 1;
            float l0 = p0[q] + bf0, l1 = p1[q] + bf1;
            float mx  = fmaxf(l0, l1);
            float lse = mx + __logf(__expf(l0 - mx) + __expf(l1 - mx));
            float val = (cls ? l1 : l0) - lse;
            out[(ebase + 4 * lg + q) * 2 + cls] = val;
        }
    }
}

// ================================================================ launch
extern "C" void kernel_launch(void* const* d_in, const int* in_sizes, int n_in,
                              void* d_out, int out_size, void* d_ws, size_t ws_size,
                              hipStream_t stream) {
    const float* x     = (const float*)d_in[0];
    const int*   ei    = (const int*)  d_in[1];
    const int*   xtext = (const int*)  d_in[2];
    const float* embed = (const float*)d_in[3];
    const float* w_ih  = (const float*)d_in[4];
    const float* w_hh  = (const float*)d_in[5];
    const float* b_ih  = (const float*)d_in[6];
    const float* b_hh  = (const float*)d_in[7];
    const float* W1    = (const float*)d_in[8];
    const float* b1    = (const float*)d_in[9];
    const float* W2    = (const float*)d_in[10];
    const float* b2    = (const float*)d_in[11];
    const float* Wl1   = (const float*)d_in[12];
    const float* bl1   = (const float*)d_in[13];
    const float* Wf    = (const float*)d_in[14];
    const float* bf    = (const float*)d_in[15];
    float* out = (float*)d_out;

    char* ws = (char*)d_ws;
    size_t off = 0;
    auto alloc = [&](size_t bytes) { char* p = ws + off; off += (bytes + 255) & ~size_t(255); return p; };
    unsigned* ht32   = (unsigned*)alloc(N_NODES * 32 * 4);
    unsigned* msb    = (unsigned*)alloc(N_NODES * 32 * 4);
    unsigned* h1b    = (unsigned*)alloc(N_NODES * 32 * 4);
    short*    h2b    = (short*)   alloc(N_NODES * 64 * 2);
    float*    dinv   = (float*)   alloc(N_NODES * 4);
    int*      cnt    = (int*)     alloc(N_NODES * 4);
    int*      excl   = (int*)     alloc(N_NODES * 4);
    int*      starts = (int*)     alloc(N_NODES * 4);
    int*      cursor = (int*)     alloc(N_NODES * 4);
    int*      bsum   = (int*)     alloc(SCAN_NB * 4);
    int*      csr_src= (int*)     alloc(N_EDGES * 4);
    short*    embbf  = (short*)   alloc(VOCAB * 64 * 2);

    // ---- bf16 embedding table
    k_embcvt<<<(VOCAB * 64 / 8 + 255) / 256, 256, 0, stream>>>(embed, embbf);

    // ---- CSR build (shared by both GCN layers)
    hipMemsetAsync(cnt, 0, N_NODES * 4, stream);
    k_count<<<(N_EDGES + 255) / 256, 256, 0, stream>>>(ei, cnt);
    k_scan_local<<<SCAN_NB, 256, 0, stream>>>(cnt, excl, bsum);
    k_scan_bsum<<<1, 256, 0, stream>>>(bsum);
    k_make_starts<<<SCAN_NB, 256, 0, stream>>>(excl, bsum, cnt, starts, cursor, dinv);
    k_fill<<<(N_EDGES + 255) / 256, 256, 0, stream>>>(ei, cursor, csr_src);

    // ---- text encoder (round-8 proven kernel)
    k_gru8<<<(NT32 + 3) / 4, 256, 0, stream>>>(xtext, embbf, w_ih, w_hh, b_ih, b_hh, ht32);

    // ---- GCN layer 1 (MFMA mm + packed gather)
    k_mm1_mf<<<(NT32 + 3) / 4, 256, 0, stream>>>(x, ht32, W1, dinv, msb);
    k_gather_p<<<(N_NODES + 7) / 8, 256, 0, stream>>>(msb, csr_src, starts, cnt, dinv, b1, h1b);

    // ---- GCN layer 2
    k_mm2_mf<<<(NT32 + 3) / 4, 256, 0, stream>>>(h1b, W2, dinv, msb);
    k_gather_h2<<<(N_NODES + 7) / 8, 256, 0, stream>>>(msb, csr_src, starts, cnt, dinv, b2, h2b);

    // ---- edge classifier (bf16 h2 fragments)
    k_edge_mfma<<<2048, 256, 0, stream>>>(ei, h2b, Wl1, bl1, Wf, bf, out);
}